// Round 9
// baseline (367.479 us; speedup 1.0000x reference)
//
#include <hip/hip_runtime.h>

typedef unsigned short u16;
typedef unsigned int u32;

#define HNUM 16
#define NSEQ 4096
#define CDIM 1024
#define SCALE 0.125f
#define LOG2E 1.4426950408889634f

using bf16x8 = __attribute__((ext_vector_type(8))) __bf16;
using f32x4  = __attribute__((ext_vector_type(4))) float;

__device__ __forceinline__ u16 f2bf(float f) {
  union { float f; u32 u; } v; v.f = f;
  u32 u = v.u;
  return (u16)((u + 0x7fffu + ((u >> 16) & 1u)) >> 16);
}
__device__ __forceinline__ float fexp2(float x) { return __builtin_amdgcn_exp2f(x); }

__device__ __forceinline__ f32x4 mfma16(bf16x8 a, bf16x8 b, f32x4 c) {
  return __builtin_amdgcn_mfma_f32_16x16x32_bf16(a, b, c, 0, 0, 0);
}

// pack 2 f32 -> 1 dword of 2 bf16 (round-half-up): lo16=bf(a), hi16=bf(b)
__device__ __forceinline__ u32 pack2(float a, float b) {
  union { float f; u32 u; } A, B;
  A.f = a; B.f = b;
  return __builtin_amdgcn_perm(B.u + 0x8000u, A.u + 0x8000u, 0x07060302u);
}

// async global->LDS, 16B/lane; LDS dest = wave-uniform base + lane*16
__device__ __forceinline__ void g2l16(const void* g, void* l) {
  __builtin_amdgcn_global_load_lds(
      (const __attribute__((address_space(1))) unsigned int*)(unsigned long long)g,
      (__attribute__((address_space(3))) unsigned int*)(unsigned int)(unsigned long long)l,
      16, 0, 0);
}

// flat f32 -> bf16 streaming convert (8 elems/thread)
__global__ __launch_bounds__(256) void cvt_k(const float* __restrict__ in,
                                             u16* __restrict__ out) {
  const int i = (blockIdx.x * 256 + threadIdx.x) * 8;
  const float4 f0 = *(const float4*)(in + i);
  const float4 f1 = *(const float4*)(in + i + 4);
  u32 d[4] = {pack2(f0.x, f0.y), pack2(f0.z, f0.w),
              pack2(f1.x, f1.y), pack2(f1.z, f1.w)};
  *(bf16x8*)(out + i) = *(bf16x8*)d;
}

// out_bf16[c*R + r] = (bf16)(in_f32[r*C + c] * (c < scaleRows ? scale : 1))
__global__ __launch_bounds__(256) void cvtT_k(const float* __restrict__ in,
                                              u16* __restrict__ out, int R, int C,
                                              int scaleRows, float scale) {
  __shared__ u16 t[64][65];
  const int tid = threadIdx.x;
  const int r0 = blockIdx.y * 64, c0 = blockIdx.x * 64;
  const int tr = tid >> 2, tc = (tid & 3) * 16;
  const float s = (c0 < scaleRows) ? scale : 1.0f;  // boundary is tile-aligned
  const float* src = in + (r0 + tr) * C + c0 + tc;
#pragma unroll
  for (int i = 0; i < 16; ++i) t[tr][tc + i] = f2bf(src[i] * s);
  __syncthreads();
  u16* dst = out + (c0 + tr) * R + r0 + tc;
#pragma unroll
  for (int i = 0; i < 16; ++i) dst[i] = t[tc + i][tr];
}

// C(MxN) = A(MxK,bf16) @ Bt(NxK,bf16)^T -> bf16. Double-buffered g2l16.
__global__ __launch_bounds__(256) void gemm1_k(const u16* __restrict__ A,
                                               const u16* __restrict__ Bt,
                                               u16* __restrict__ C,
                                               int M, int N, int K) {
  __shared__ __align__(16) u16 As[2][128 * 64];
  __shared__ __align__(16) u16 Bs[2][128 * 64];
  const int tid = threadIdx.x;
  const int wave = tid >> 6, lane = tid & 63;
  const int quad = lane >> 4, l16 = lane & 15;
  const int m0 = blockIdx.y * 128, n0 = blockIdx.x * 128;
  const int wm = (wave >> 1) * 64, wn = (wave & 1) * 64;
  const int lrow = lane >> 3, lc8 = (lane & 7) * 8;

  f32x4 acc[4][4] = {};
  // prologue: stage k0=0 into buf 0
#pragma unroll
  for (int c = 0; c < 4; ++c) {
    const int cw = wave * 4 + c;
    g2l16(A  + (m0 + cw * 8 + lrow) * K + lc8, (char*)As[0] + cw * 1024);
    g2l16(Bt + (n0 + cw * 8 + lrow) * K + lc8, (char*)Bs[0] + cw * 1024);
  }
  const int NIT = K / 64;
  for (int it = 0; it < NIT; ++it) {
    const int cur = it & 1;
    __syncthreads();  // publishes buf[cur]; also fences iter it-1's reads
    if (it + 1 < NIT) {
      const int k0 = (it + 1) * 64;
#pragma unroll
      for (int c = 0; c < 4; ++c) {
        const int cw = wave * 4 + c;
        g2l16(A  + (m0 + cw * 8 + lrow) * K + k0 + lc8, (char*)As[1 - cur] + cw * 1024);
        g2l16(Bt + (n0 + cw * 8 + lrow) * K + k0 + lc8, (char*)Bs[1 - cur] + cw * 1024);
      }
    }
#pragma unroll
    for (int ks = 0; ks < 2; ++ks) {
      bf16x8 a[4], b[4];
#pragma unroll
      for (int mt = 0; mt < 4; ++mt)
        a[mt] = *(const bf16x8*)(As[cur] + (wm + mt * 16 + l16) * 64 + ks * 32 + quad * 8);
#pragma unroll
      for (int nt = 0; nt < 4; ++nt)
        b[nt] = *(const bf16x8*)(Bs[cur] + (wn + nt * 16 + l16) * 64 + ks * 32 + quad * 8);
#pragma unroll
      for (int mt = 0; mt < 4; ++mt)
#pragma unroll
        for (int nt = 0; nt < 4; ++nt)
          acc[mt][nt] = mfma16(a[mt], b[nt], acc[mt][nt]);
    }
  }
#pragma unroll
  for (int mt = 0; mt < 4; ++mt)
#pragma unroll
    for (int nt = 0; nt < 4; ++nt)
#pragma unroll
      for (int r = 0; r < 4; ++r)
        C[(m0 + wm + mt * 16 + quad * 4 + r) * N + n0 + wn + nt * 16 + l16] =
            f2bf(acc[mt][nt][r]);
}

// out = Obf(bf16, MxK) @ WpT(bf16, NxK)^T + bias(f32) -> f32.
// 128M x 64N tiles, double-buffered g2l16.
__global__ __launch_bounds__(256) void gemm2_k(const u16* __restrict__ A,
                                               const u16* __restrict__ Bt,
                                               float* __restrict__ C,
                                               const float* __restrict__ bias,
                                               int M, int N, int K) {
  __shared__ __align__(16) u16 As[2][128 * 64];
  __shared__ __align__(16) u16 Bs[2][64 * 64];
  const int tid = threadIdx.x;
  const int wave = tid >> 6, lane = tid & 63;
  const int quad = lane >> 4, l16 = lane & 15;
  const int m0 = blockIdx.y * 128, n0 = blockIdx.x * 64;
  const int wm = wave * 32;
  const int lrow = lane >> 3, lc8 = (lane & 7) * 8;

  f32x4 acc[2][4] = {};
#pragma unroll
  for (int c = 0; c < 4; ++c) {
    const int cw = wave * 4 + c;
    g2l16(A + (m0 + cw * 8 + lrow) * K + lc8, (char*)As[0] + cw * 1024);
  }
#pragma unroll
  for (int c = 0; c < 2; ++c) {
    const int cw = wave * 2 + c;
    g2l16(Bt + (n0 + cw * 8 + lrow) * K + lc8, (char*)Bs[0] + cw * 1024);
  }
  const int NIT = K / 64;
  for (int it = 0; it < NIT; ++it) {
    const int cur = it & 1;
    __syncthreads();
    if (it + 1 < NIT) {
      const int k0 = (it + 1) * 64;
#pragma unroll
      for (int c = 0; c < 4; ++c) {
        const int cw = wave * 4 + c;
        g2l16(A + (m0 + cw * 8 + lrow) * K + k0 + lc8, (char*)As[1 - cur] + cw * 1024);
      }
#pragma unroll
      for (int c = 0; c < 2; ++c) {
        const int cw = wave * 2 + c;
        g2l16(Bt + (n0 + cw * 8 + lrow) * K + k0 + lc8, (char*)Bs[1 - cur] + cw * 1024);
      }
    }
#pragma unroll
    for (int ks = 0; ks < 2; ++ks) {
      bf16x8 a[2], b[4];
#pragma unroll
      for (int mt = 0; mt < 2; ++mt)
        a[mt] = *(const bf16x8*)(As[cur] + (wm + mt * 16 + l16) * 64 + ks * 32 + quad * 8);
#pragma unroll
      for (int nt = 0; nt < 4; ++nt)
        b[nt] = *(const bf16x8*)(Bs[cur] + (nt * 16 + l16) * 64 + ks * 32 + quad * 8);
#pragma unroll
      for (int mt = 0; mt < 2; ++mt)
#pragma unroll
        for (int nt = 0; nt < 4; ++nt)
          acc[mt][nt] = mfma16(a[mt], b[nt], acc[mt][nt]);
    }
  }
#pragma unroll
  for (int mt = 0; mt < 2; ++mt)
#pragma unroll
    for (int nt = 0; nt < 4; ++nt)
#pragma unroll
      for (int r = 0; r < 4; ++r) {
        const int col = n0 + nt * 16 + l16;
        C[(m0 + wm + mt * 16 + quad * 4 + r) * N + col] = acc[mt][nt][r] + bias[col];
      }
}

// Flash attention v8: BARRIER-FREE. K and V fragments are loaded directly
// global->VGPR in MFMA lane layout (16B/lane; 16 rows x 64B per instr, served
// by L1/L2 — co-resident blocks share the head so tiles are cache-hot).
// No __syncthreads, no K/V staging, LDS only for the per-wave P round-trip.
// kf double-buffered across iterations (loads overlap exp2+PV of prev tile);
// vf loaded at iter top (loads overlap the S-phase).
__global__ __launch_bounds__(128) void attn_k(const u16* __restrict__ QK,
                                              const u16* __restrict__ Vt,
                                              u16* __restrict__ O) {
  __shared__ __align__(16) u16 Ps[2][32 * 64];  // per-wave [q][key] bf16, swizzled
  const int tid = threadIdx.x;
  const int wave = tid >> 6, lane = tid & 63;
  const int quad = lane >> 4, l16 = lane & 15;
  const int head = blockIdx.y;
  const int qb = blockIdx.x * 64 + wave * 32;
  const int swz = (quad ^ (l16 & 7)) * 8;  // Ps frag-read swizzle base (ks=0)

  // global fragment bases (A-frag for K, B-frag for V)
  const u16* kbase = QK + l16 * 2048 + CDIM + head * 64 + quad * 8;
  const u16* vbase = Vt + (head * 64 + l16) * 4096 + quad * 8;

  // Q B-frags in regs for the whole kernel: B[n=q=l16][k=d=quad*8+j]
  bf16x8 qf[2][2];
#pragma unroll
  for (int mt = 0; mt < 2; ++mt)
#pragma unroll
    for (int ks = 0; ks < 2; ++ks)
      qf[mt][ks] = *(const bf16x8*)(QK + (qb + mt * 16 + l16) * 2048 + head * 64 +
                                    ks * 32 + quad * 8);

  f32x4 o[2][4] = {};  // [mt(q)][dt(d)]
  float lsum[2] = {};  // row-sum for q = mt*16 + l16
  u16* Pw = Ps[wave];

  // prefetch kf for tile 0: A[m=key=nt*16+l16][k=d=ks*32+quad*8..]
  bf16x8 kf[2][4];  // [ks][nt]
#pragma unroll
  for (int ks = 0; ks < 2; ++ks)
#pragma unroll
    for (int nt = 0; nt < 4; ++nt)
      kf[ks][nt] = *(const bf16x8*)(kbase + (nt * 16) * 2048 + ks * 32);

  for (int kt0 = 0; kt0 < NSEQ; kt0 += 64) {
    // vf for current tile: B[n=d=dt*16+l16][k=key=ks*32+quad*8..]
    bf16x8 vf[2][4];  // [ks][dt]
#pragma unroll
    for (int ks = 0; ks < 2; ++ks)
#pragma unroll
      for (int dt = 0; dt < 4; ++dt)
        vf[ks][dt] = *(const bf16x8*)(vbase + (dt * 16) * 4096 + kt0 + ks * 32);

    // S^T (64 keys x 32 q per wave) = K @ Q^T
    f32x4 s[2][4] = {};  // [mt(q-tile)][nt(key-tile)]
#pragma unroll
    for (int ks = 0; ks < 2; ++ks)
#pragma unroll
      for (int nt = 0; nt < 4; ++nt)
#pragma unroll
        for (int mt = 0; mt < 2; ++mt)
          s[mt][nt] = mfma16(kf[ks][nt], qf[mt][ks], s[mt][nt]);

    // prefetch kf for next tile (overlaps exp2 + P round-trip + PV)
    if (kt0 + 64 < NSEQ) {
#pragma unroll
      for (int ks = 0; ks < 2; ++ks)
#pragma unroll
        for (int nt = 0; nt < 4; ++nt)
          kf[ks][nt] =
              *(const bf16x8*)(kbase + (kt0 + 64 + nt * 16) * 2048 + ks * 32);
    }

    // p = exp2(s); in-register row sums; packed b64 write to Ps[q][key]
#pragma unroll
    for (int mt = 0; mt < 2; ++mt)
#pragma unroll
      for (int nt = 0; nt < 4; ++nt) {
        const float p0 = fexp2(s[mt][nt][0]);
        const float p1 = fexp2(s[mt][nt][1]);
        const float p2 = fexp2(s[mt][nt][2]);
        const float p3 = fexp2(s[mt][nt][3]);
        lsum[mt] += (p0 + p1) + (p2 + p3);
        u32 d01 = pack2(p0, p1), d23 = pack2(p2, p3);
        // element (q = mt*16+l16, keys nt*16+quad*4 .. +3)
        const int col8 = (nt * 2 + (quad >> 1)) ^ (l16 & 7);
        u32* dst = (u32*)(Pw + (mt * 16 + l16) * 64 + col8 * 8 + (quad & 1) * 4);
        dst[0] = d01; dst[1] = d23;  // ds_write_b64
      }

    // O += P @ V  (A = P[q][key] b128 frags from per-wave LDS, B = vf regs)
#pragma unroll
    for (int ks = 0; ks < 2; ++ks) {
      bf16x8 pf[2];
#pragma unroll
      for (int mt = 0; mt < 2; ++mt)
        pf[mt] = *(const bf16x8*)(Pw + (mt * 16 + l16) * 64 + (swz ^ (ks * 32)));
#pragma unroll
      for (int dt = 0; dt < 4; ++dt)
#pragma unroll
        for (int mt = 0; mt < 2; ++mt)
          o[mt][dt] = mfma16(pf[mt], vf[ks][dt], o[mt][dt]);
    }
  }

  // finalize row sums (reduce over quads), broadcast to C-layout rows, store
  float linv[2];
#pragma unroll
  for (int mt = 0; mt < 2; ++mt) {
    float v = lsum[mt];
    v += __shfl_xor(v, 16, 64);
    v += __shfl_xor(v, 32, 64);
    linv[mt] = 1.0f / v;
  }
#pragma unroll
  for (int mt = 0; mt < 2; ++mt)
#pragma unroll
    for (int r = 0; r < 4; ++r) {
      // linv for q-row quad*4+r lives in lane with l16 = quad*4+r
      const float lv = __shfl(linv[mt], (lane & 48) | (quad * 4 + r), 64);
#pragma unroll
      for (int dt = 0; dt < 4; ++dt)
        O[(qb + mt * 16 + quad * 4 + r) * CDIM + head * 64 + dt * 16 + l16] =
            f2bf(o[mt][dt][r] * lv);
    }
}

extern "C" void kernel_launch(void* const* d_in, const int* in_sizes, int n_in,
                              void* d_out, int out_size, void* d_ws, size_t ws_size,
                              hipStream_t stream) {
  const float* x1    = (const float*)d_in[0];  // 4096x1024 f32
  const float* x2    = (const float*)d_in[1];  // 4096x1024 f32
  const float* Wqkv  = (const float*)d_in[2];  // 1024x2048 f32
  const float* Wproj = (const float*)d_in[3];  // 1024x1024 f32
  const float* bproj = (const float*)d_in[4];  // 1024 f32
  float* out = (float*)d_out;                  // 4096x1024 f32

  char* ws = (char*)d_ws;
  u16* QK  = (u16*)(ws);                      // 4096x2048 bf16 (16MB)
  u16* Vt  = (u16*)(ws + 16u * 1024 * 1024);  // 1024x4096 bf16 (8MB)
  u16* Obf = (u16*)(ws + 24u * 1024 * 1024);  // 4096x1024 bf16 (8MB)
  u16* WpT = (u16*)(ws + 32u * 1024 * 1024);  // 1024x1024 bf16 (2MB)
  u16* WqT = (u16*)(ws + 34u * 1024 * 1024);  // 2048x1024 bf16 (4MB)
  u16* x1b = (u16*)(ws + 38u * 1024 * 1024);  // 4096x1024 bf16 (8MB)

  const float cfac = SCALE * LOG2E;  // softmax scale folded into q-cols of Wqkv

  cvt_k<<<dim3(4096 * 1024 / 2048), 256, 0, stream>>>(x1, x1b);
  cvtT_k<<<dim3(2048 / 64, 1024 / 64), 256, 0, stream>>>(Wqkv, WqT, 1024, 2048,
                                                         1024, cfac);
  cvtT_k<<<dim3(1024 / 64, 1024 / 64), 256, 0, stream>>>(Wproj, WpT, 1024, 1024,
                                                         0, 1.0f);
  cvtT_k<<<dim3(1024 / 64, 4096 / 64), 256, 0, stream>>>(x2, Vt, 4096, 1024,
                                                         0, 1.0f);

  gemm1_k<<<dim3(2048 / 128, 4096 / 128), 256, 0, stream>>>(x1b, WqT, QK,
                                                            4096, 2048, 1024);
  attn_k<<<dim3(4096 / 64, HNUM), 128, 0, stream>>>(QK, Vt, Obf);
  gemm2_k<<<dim3(1024 / 64, 4096 / 128), 256, 0, stream>>>(Obf, WpT, out, bproj,
                                                           4096, 1024, 1024);
}

// Round 10
// 247.914 us; speedup vs baseline: 1.4823x; 1.4823x over previous
//
#include <hip/hip_runtime.h>

typedef unsigned short u16;
typedef unsigned int u32;

#define HNUM 16
#define NSEQ 4096
#define CDIM 1024
#define SCALE 0.125f
#define LOG2E 1.4426950408889634f

using bf16x8 = __attribute__((ext_vector_type(8))) __bf16;
using f32x4  = __attribute__((ext_vector_type(4))) float;

__device__ __forceinline__ u16 f2bf(float f) {
  union { float f; u32 u; } v; v.f = f;
  u32 u = v.u;
  return (u16)((u + 0x7fffu + ((u >> 16) & 1u)) >> 16);
}
__device__ __forceinline__ float fexp2(float x) { return __builtin_amdgcn_exp2f(x); }

__device__ __forceinline__ f32x4 mfma16(bf16x8 a, bf16x8 b, f32x4 c) {
  return __builtin_amdgcn_mfma_f32_16x16x32_bf16(a, b, c, 0, 0, 0);
}

// pack 2 f32 -> 1 dword of 2 bf16 (round-half-up): lo16=bf(a), hi16=bf(b)
__device__ __forceinline__ u32 pack2(float a, float b) {
  union { float f; u32 u; } A, B;
  A.f = a; B.f = b;
  return __builtin_amdgcn_perm(B.u + 0x8000u, A.u + 0x8000u, 0x07060302u);
}

// async global->LDS, 16B/lane; LDS dest = wave-uniform base + lane*16
__device__ __forceinline__ void g2l16(const void* g, void* l) {
  __builtin_amdgcn_global_load_lds(
      (const __attribute__((address_space(1))) unsigned int*)(unsigned long long)g,
      (__attribute__((address_space(3))) unsigned int*)(unsigned int)(unsigned long long)l,
      16, 0, 0);
}

// ---- merged prep kernel: x1 cvt + 3 convert-transposes, range-dispatched ----
__device__ __forceinline__ void cvtT_body(const float* __restrict__ in,
                                          u16* __restrict__ out, int R, int C,
                                          int bx, int by, float scale, int tid) {
  __shared__ u16 t[64][65];
  const int r0 = by * 64, c0 = bx * 64;
  const int tr = tid >> 2, tc = (tid & 3) * 16;
  const float* src = in + (r0 + tr) * C + c0 + tc;
#pragma unroll
  for (int i = 0; i < 16; ++i) t[tr][tc + i] = f2bf(src[i] * scale);
  __syncthreads();
  u16* dst = out + (c0 + tr) * R + r0 + tc;
#pragma unroll
  for (int i = 0; i < 16; ++i) dst[i] = t[tc + i][tr];
}

// blocks: [0,2048) x1 cvt | [2048,2560) Wqkv T | [2560,2816) Wproj T | [2816,3840) x2 T
__global__ __launch_bounds__(256) void prep_k(const float* __restrict__ x1,
                                              u16* __restrict__ x1b,
                                              const float* __restrict__ Wqkv,
                                              u16* __restrict__ WqT,
                                              const float* __restrict__ Wproj,
                                              u16* __restrict__ WpT,
                                              const float* __restrict__ x2,
                                              u16* __restrict__ Vt,
                                              float cfac) {
  const int b = blockIdx.x, tid = threadIdx.x;
  if (b < 2048) {
    const int i = (b * 256 + tid) * 8;
    const float4 f0 = *(const float4*)(x1 + i);
    const float4 f1 = *(const float4*)(x1 + i + 4);
    u32 d[4] = {pack2(f0.x, f0.y), pack2(f0.z, f0.w),
                pack2(f1.x, f1.y), pack2(f1.z, f1.w)};
    *(bf16x8*)(x1b + i) = *(bf16x8*)d;
  } else if (b < 2560) {
    const int rel = b - 2048;                     // Wqkv: R=1024 C=2048, 32x16
    const int bx = rel & 31, by = rel >> 5;
    cvtT_body(Wqkv, WqT, 1024, 2048, bx, by, bx < 16 ? cfac : 1.0f, tid);
  } else if (b < 2816) {
    const int rel = b - 2560;                     // Wproj: R=C=1024, 16x16
    const int bx = rel & 15, by = rel >> 4;
    cvtT_body(Wproj, WpT, 1024, 1024, bx, by, 1.0f, tid);
  } else {
    const int rel = b - 2816;                     // x2: R=4096 C=1024, 16x64
    const int bx = rel & 15, by = rel >> 4;
    cvtT_body(x2, Vt, 4096, 1024, bx, by, 1.0f, tid);
  }
}

// QK = x1b(bf16 MxK) @ WqT(bf16 NxK)^T -> bf16. 128M x 64N tiles, single-buffer,
// 1024 blocks = 4/CU = 16 waves/CU (occupancy-based latency hiding).
__global__ __launch_bounds__(256) void gemm1_k(const u16* __restrict__ A,
                                               const u16* __restrict__ Bt,
                                               u16* __restrict__ C,
                                               int M, int N, int K) {
  __shared__ __align__(16) u16 As[128 * 64];
  __shared__ __align__(16) u16 Bs[64 * 64];
  const int tid = threadIdx.x;
  const int wave = tid >> 6, lane = tid & 63;
  const int quad = lane >> 4, l16 = lane & 15;
  const int m0 = blockIdx.y * 128, n0 = blockIdx.x * 64;
  const int wm = wave * 32;
  const int lrow = lane >> 3, lc8 = (lane & 7) * 8;

  f32x4 acc[2][4] = {};
  for (int k0 = 0; k0 < K; k0 += 64) {
#pragma unroll
    for (int c = 0; c < 4; ++c) {
      const int cw = wave * 4 + c;
      g2l16(A + (m0 + cw * 8 + lrow) * K + k0 + lc8, (char*)As + cw * 1024);
    }
#pragma unroll
    for (int c = 0; c < 2; ++c) {
      const int cw = wave * 2 + c;
      g2l16(Bt + (n0 + cw * 8 + lrow) * K + k0 + lc8, (char*)Bs + cw * 1024);
    }
    __syncthreads();
#pragma unroll
    for (int ks = 0; ks < 2; ++ks) {
      bf16x8 a[2], b[4];
#pragma unroll
      for (int mt = 0; mt < 2; ++mt)
        a[mt] = *(const bf16x8*)(As + (wm + mt * 16 + l16) * 64 + ks * 32 + quad * 8);
#pragma unroll
      for (int nt = 0; nt < 4; ++nt)
        b[nt] = *(const bf16x8*)(Bs + (nt * 16 + l16) * 64 + ks * 32 + quad * 8);
#pragma unroll
      for (int mt = 0; mt < 2; ++mt)
#pragma unroll
        for (int nt = 0; nt < 4; ++nt)
          acc[mt][nt] = mfma16(a[mt], b[nt], acc[mt][nt]);
    }
    __syncthreads();
  }
#pragma unroll
  for (int mt = 0; mt < 2; ++mt)
#pragma unroll
    for (int nt = 0; nt < 4; ++nt)
#pragma unroll
      for (int r = 0; r < 4; ++r)
        C[(m0 + wm + mt * 16 + quad * 4 + r) * N + n0 + nt * 16 + l16] =
            f2bf(acc[mt][nt][r]);
}

// out = Obf(bf16 MxK) @ WpT(bf16 NxK)^T + bias(f32) -> f32. 128x64, dbuf.
__global__ __launch_bounds__(256) void gemm2_k(const u16* __restrict__ A,
                                               const u16* __restrict__ Bt,
                                               float* __restrict__ C,
                                               const float* __restrict__ bias,
                                               int M, int N, int K) {
  __shared__ __align__(16) u16 As[2][128 * 64];
  __shared__ __align__(16) u16 Bs[2][64 * 64];
  const int tid = threadIdx.x;
  const int wave = tid >> 6, lane = tid & 63;
  const int quad = lane >> 4, l16 = lane & 15;
  const int m0 = blockIdx.y * 128, n0 = blockIdx.x * 64;
  const int wm = wave * 32;
  const int lrow = lane >> 3, lc8 = (lane & 7) * 8;

  f32x4 acc[2][4] = {};
#pragma unroll
  for (int c = 0; c < 4; ++c) {
    const int cw = wave * 4 + c;
    g2l16(A + (m0 + cw * 8 + lrow) * K + lc8, (char*)As[0] + cw * 1024);
  }
#pragma unroll
  for (int c = 0; c < 2; ++c) {
    const int cw = wave * 2 + c;
    g2l16(Bt + (n0 + cw * 8 + lrow) * K + lc8, (char*)Bs[0] + cw * 1024);
  }
  const int NIT = K / 64;
  for (int it = 0; it < NIT; ++it) {
    const int cur = it & 1;
    __syncthreads();
    if (it + 1 < NIT) {
      const int k0 = (it + 1) * 64;
#pragma unroll
      for (int c = 0; c < 4; ++c) {
        const int cw = wave * 4 + c;
        g2l16(A + (m0 + cw * 8 + lrow) * K + k0 + lc8, (char*)As[1 - cur] + cw * 1024);
      }
#pragma unroll
      for (int c = 0; c < 2; ++c) {
        const int cw = wave * 2 + c;
        g2l16(Bt + (n0 + cw * 8 + lrow) * K + k0 + lc8, (char*)Bs[1 - cur] + cw * 1024);
      }
    }
#pragma unroll
    for (int ks = 0; ks < 2; ++ks) {
      bf16x8 a[2], b[4];
#pragma unroll
      for (int mt = 0; mt < 2; ++mt)
        a[mt] = *(const bf16x8*)(As[cur] + (wm + mt * 16 + l16) * 64 + ks * 32 + quad * 8);
#pragma unroll
      for (int nt = 0; nt < 4; ++nt)
        b[nt] = *(const bf16x8*)(Bs[cur] + (nt * 16 + l16) * 64 + ks * 32 + quad * 8);
#pragma unroll
      for (int mt = 0; mt < 2; ++mt)
#pragma unroll
        for (int nt = 0; nt < 4; ++nt)
          acc[mt][nt] = mfma16(a[mt], b[nt], acc[mt][nt]);
    }
  }
#pragma unroll
  for (int mt = 0; mt < 2; ++mt)
#pragma unroll
    for (int nt = 0; nt < 4; ++nt)
#pragma unroll
      for (int r = 0; r < 4; ++r) {
        const int col = n0 + nt * 16 + l16;
        C[(m0 + wm + mt * 16 + quad * 4 + r) * N + col] = acc[mt][nt][r] + bias[col];
      }
}

// Flash attention v5 (round-7 best, 125.3us): S^T scheme + dbuf async K/V.
// Wave owns 32 q-rows; block = 2 waves; 1024 blocks; LDS 40KB.
__global__ __launch_bounds__(128) void attn_k(const u16* __restrict__ QK,
                                              const u16* __restrict__ Vt,
                                              u16* __restrict__ O) {
  __shared__ __align__(16) u16 Ks[2][64 * 64];  // [key][d], swizzled
  __shared__ __align__(16) u16 Vs[2][64 * 64];  // [d][key], swizzled
  __shared__ __align__(16) u16 Ps[2][32 * 64];  // per-wave [q][key] bf16, swizzled
  const int tid = threadIdx.x;
  const int wave = tid >> 6, lane = tid & 63;
  const int quad = lane >> 4, l16 = lane & 15;
  const int head = blockIdx.y;
  const int qb = blockIdx.x * 64 + wave * 32;
  const int lrow = lane >> 3;               // staging row within 8-row chunk
  const int lc8 = ((lane & 7) ^ lrow) * 8;  // staging logical col (u16 units)
  const int swz = (quad ^ (l16 & 7)) * 8;   // frag-read swizzle base (ks=0)

  const u16* kp[4];
  const u16* vp[4];
#pragma unroll
  for (int c = 0; c < 4; ++c) {
    const int row = (wave * 4 + c) * 8 + lrow;
    kp[c] = QK + row * 2048 + CDIM + head * 64 + lc8;  // +64*2048 per iter
    vp[c] = Vt + (head * 64 + row) * NSEQ + lc8;       // +64 per iter
  }

  bf16x8 qf[2][2];
#pragma unroll
  for (int mt = 0; mt < 2; ++mt)
#pragma unroll
    for (int ks = 0; ks < 2; ++ks)
      qf[mt][ks] = *(const bf16x8*)(QK + (qb + mt * 16 + l16) * 2048 + head * 64 +
                                    ks * 32 + quad * 8);

  f32x4 o[2][4] = {};
  float lsum[2] = {};
  u16* Pw = Ps[wave];

#pragma unroll
  for (int c = 0; c < 4; ++c) {
    const int cw = wave * 4 + c;
    g2l16(kp[c], (char*)Ks[0] + cw * 1024);
    g2l16(vp[c], (char*)Vs[0] + cw * 1024);
    kp[c] += 64 * 2048;
    vp[c] += 64;
  }

  for (int kt = 0; kt < NSEQ / 64; ++kt) {
    const int cur = kt & 1;
    __syncthreads();  // publishes buf[cur]

    if (kt < NSEQ / 64 - 1) {
#pragma unroll
      for (int c = 0; c < 4; ++c) {
        const int cw = wave * 4 + c;
        g2l16(kp[c], (char*)Ks[1 - cur] + cw * 1024);
        g2l16(vp[c], (char*)Vs[1 - cur] + cw * 1024);
        kp[c] += 64 * 2048;
        vp[c] += 64;
      }
    }

    const u16* Kc = Ks[cur];
    const u16* Vc = Vs[cur];

    f32x4 s[2][4] = {};
#pragma unroll
    for (int ks = 0; ks < 2; ++ks)
#pragma unroll
      for (int nt = 0; nt < 4; ++nt) {
        const bf16x8 kf =
            *(const bf16x8*)(Kc + (nt * 16 + l16) * 64 + (swz ^ (ks * 32)));
#pragma unroll
        for (int mt = 0; mt < 2; ++mt)
          s[mt][nt] = mfma16(kf, qf[mt][ks], s[mt][nt]);
      }

#pragma unroll
    for (int mt = 0; mt < 2; ++mt)
#pragma unroll
      for (int nt = 0; nt < 4; ++nt) {
        const float p0 = fexp2(s[mt][nt][0]);
        const float p1 = fexp2(s[mt][nt][1]);
        const float p2 = fexp2(s[mt][nt][2]);
        const float p3 = fexp2(s[mt][nt][3]);
        lsum[mt] += (p0 + p1) + (p2 + p3);
        u32 d01 = pack2(p0, p1), d23 = pack2(p2, p3);
        const int col8 = (nt * 2 + (quad >> 1)) ^ (l16 & 7);
        u32* dst = (u32*)(Pw + (mt * 16 + l16) * 64 + col8 * 8 + (quad & 1) * 4);
        dst[0] = d01; dst[1] = d23;  // ds_write_b64
      }

#pragma unroll
    for (int ks = 0; ks < 2; ++ks) {
      bf16x8 pf[2];
#pragma unroll
      for (int mt = 0; mt < 2; ++mt)
        pf[mt] = *(const bf16x8*)(Pw + (mt * 16 + l16) * 64 + (swz ^ (ks * 32)));
#pragma unroll
      for (int dt = 0; dt < 4; ++dt) {
        const bf16x8 vf =
            *(const bf16x8*)(Vc + (dt * 16 + l16) * 64 + (swz ^ (ks * 32)));
#pragma unroll
        for (int mt = 0; mt < 2; ++mt)
          o[mt][dt] = mfma16(pf[mt], vf, o[mt][dt]);
      }
    }
  }

  float linv[2];
#pragma unroll
  for (int mt = 0; mt < 2; ++mt) {
    float v = lsum[mt];
    v += __shfl_xor(v, 16, 64);
    v += __shfl_xor(v, 32, 64);
    linv[mt] = 1.0f / v;
  }
#pragma unroll
  for (int mt = 0; mt < 2; ++mt)
#pragma unroll
    for (int r = 0; r < 4; ++r) {
      const float lv = __shfl(linv[mt], (lane & 48) | (quad * 4 + r), 64);
#pragma unroll
      for (int dt = 0; dt < 4; ++dt)
        O[(qb + mt * 16 + quad * 4 + r) * CDIM + head * 64 + dt * 16 + l16] =
            f2bf(o[mt][dt][r] * lv);
    }
}

extern "C" void kernel_launch(void* const* d_in, const int* in_sizes, int n_in,
                              void* d_out, int out_size, void* d_ws, size_t ws_size,
                              hipStream_t stream) {
  const float* x1    = (const float*)d_in[0];  // 4096x1024 f32
  const float* x2    = (const float*)d_in[1];  // 4096x1024 f32
  const float* Wqkv  = (const float*)d_in[2];  // 1024x2048 f32
  const float* Wproj = (const float*)d_in[3];  // 1024x1024 f32
  const float* bproj = (const float*)d_in[4];  // 1024 f32
  float* out = (float*)d_out;                  // 4096x1024 f32

  char* ws = (char*)d_ws;
  u16* QK  = (u16*)(ws);                      // 4096x2048 bf16 (16MB)
  u16* Vt  = (u16*)(ws + 16u * 1024 * 1024);  // 1024x4096 bf16 (8MB)
  u16* Obf = (u16*)(ws + 24u * 1024 * 1024);  // 4096x1024 bf16 (8MB)
  u16* WpT = (u16*)(ws + 32u * 1024 * 1024);  // 1024x1024 bf16 (2MB)
  u16* WqT = (u16*)(ws + 34u * 1024 * 1024);  // 2048x1024 bf16 (4MB)
  u16* x1b = (u16*)(ws + 38u * 1024 * 1024);  // 4096x1024 bf16 (8MB)

  const float cfac = SCALE * LOG2E;  // softmax scale folded into q-cols of Wqkv

  prep_k<<<dim3(3840), 256, 0, stream>>>(x1, x1b, Wqkv, WqT, Wproj, WpT, x2, Vt,
                                         cfac);
  gemm1_k<<<dim3(2048 / 64, 4096 / 128), 256, 0, stream>>>(x1b, WqT, QK,
                                                           4096, 2048, 1024);
  attn_k<<<dim3(4096 / 64, HNUM), 128, 0, stream>>>(QK, Vt, Obf);
  gemm2_k<<<dim3(1024 / 64, 4096 / 128), 256, 0, stream>>>(Obf, WpT, out, bproj,
                                                           4096, 1024, 1024);
}